// Round 1
// baseline (2122.807 us; speedup 1.0000x reference)
//
#include <hip/hip_runtime.h>

#define DIN 100
#define DD  64
#define NE  250000
#define NB  16
#define NN  50000
#define NR  500
#define NM  500000

// workspace layout (float offsets)
#define TA_OFF   64
#define TA2_OFF  (TA_OFF + NM*DD)
#define HU2_OFF  (TA2_OFF + NE*DD)
#define RT_OFF   (HU2_OFF + NN*DD)
#define QT_OFF   (RT_OFF + 4*NR*DD)
#define LG_OFF   (QT_OFF + 4*NB*DD)

__device__ __forceinline__ void fma4x4(const float4 x, const float4 w, float4 acc[4]) {
  acc[0].x += x.x*w.x; acc[0].y += x.x*w.y; acc[0].z += x.x*w.z; acc[0].w += x.x*w.w;
  acc[1].x += x.y*w.x; acc[1].y += x.y*w.y; acc[1].z += x.y*w.z; acc[1].w += x.y*w.w;
  acc[2].x += x.z*w.x; acc[2].y += x.z*w.y; acc[2].z += x.z*w.z; acc[2].w += x.z*w.w;
  acc[3].x += x.w*w.x; acc[3].y += x.w*w.y; acc[3].z += x.w*w.z; acc[3].w += x.w*w.w;
}

__device__ __forceinline__ float4 leaky4(float4 v) {
  v.x = v.x > 0.f ? v.x : 0.2f*v.x;
  v.y = v.y > 0.f ? v.y : 0.2f*v.y;
  v.z = v.z > 0.f ? v.z : 0.2f*v.z;
  v.w = v.w > 0.f ? v.w : 0.2f*v.w;
  return v;
}

__global__ void k_init(int* wsI, float* bsum) {
  if (threadIdx.x == 0) { wsI[0] = 0x7fffffff; wsI[1] = 0; }
  if (threadIdx.x < NB) bsum[threadIdx.x] = 0.f;
}

__global__ void k_limits(const int* __restrict__ edges, int* __restrict__ wsI) {
  int i = blockIdx.x * blockDim.x + threadIdx.x;
  int mn = 0x7fffffff, mx = -1;
  if (i < NE) { int v = edges[i*8 + 7]; mn = v; mx = v; }
  for (int off = 32; off > 0; off >>= 1) {
    mn = min(mn, __shfl_down(mn, off));
    mx = max(mx, __shfl_down(mx, off));
  }
  if ((threadIdx.x & 63) == 0) {
    atomicMin(&wsI[0], mn);
    atomicMax(&wsI[1], mx + 1);
  }
}

// one 64-thread block per (rel row | batch row): builds per-rel / per-batch tables
__global__ void k_tables(const float* __restrict__ rtab,
                         const float* __restrict__ qh, const float* __restrict__ qr,
                         const float* __restrict__ pW, const float* __restrict__ pb,
                         const float* __restrict__ g1_lW, const float* __restrict__ g1_lb,
                         const float* __restrict__ g1_rW, const float* __restrict__ g1_rb,
                         const float* __restrict__ g2_lW, const float* __restrict__ g2_lb,
                         const float* __restrict__ g2_rW, const float* __restrict__ g2_rb,
                         float* __restrict__ rT, float* __restrict__ qT) {
  __shared__ float xs[DIN], xs2[DIN], ps[DD], ps2[DD];
  const int d = threadIdx.x;
  const int blk = blockIdx.x;
  if (blk < NR) {
    for (int k = d; k < DIN; k += 64) xs[k] = rtab[blk*DIN + k];
    __syncthreads();
    float a = pb[d];
    for (int k = 0; k < DIN; ++k) a += xs[k] * pW[k*DD + d];
    ps[d] = tanhf(a);
    __syncthreads();
    float o1 = 0.f, o2 = 0.f, o3 = 0.f, o4 = 0.f;
    for (int k = 0; k < DD; ++k) {
      float p = ps[k];
      o1 += p * g1_lW[(DD + k)*DD + d];
      o2 += p * g1_rW[(DD + k)*DD + d];
      o3 += p * g2_lW[(DD + k)*DD + d];
      o4 += p * g2_rW[(DD + k)*DD + d];
    }
    rT[(0*NR + blk)*DD + d] = o1;
    rT[(1*NR + blk)*DD + d] = o2;
    rT[(2*NR + blk)*DD + d] = o3;
    rT[(3*NR + blk)*DD + d] = o4;
  } else {
    const int b = blk - NR;
    for (int k = d; k < DIN; k += 64) { xs[k] = qh[b*DIN + k]; xs2[k] = qr[b*DIN + k]; }
    __syncthreads();
    float a = pb[d], a2 = pb[d];
    for (int k = 0; k < DIN; ++k) { a += xs[k]*pW[k*DD + d]; a2 += xs2[k]*pW[k*DD + d]; }
    ps[d] = tanhf(a); ps2[d] = tanhf(a2);
    __syncthreads();
    float o1 = g1_lb[d], o2 = g1_rb[d], o3 = g2_lb[d], o4 = g2_rb[d];
    for (int k = 0; k < DD; ++k) {
      float p = ps[k], p2 = ps2[k];
      o1 += p * g1_lW[(2*DD + k)*DD + d] + p2 * g1_lW[(3*DD + k)*DD + d];
      o2 += p * g1_rW[(2*DD + k)*DD + d] + p2 * g1_rW[(3*DD + k)*DD + d];
      o3 += p * g2_lW[(2*DD + k)*DD + d] + p2 * g2_lW[(3*DD + k)*DD + d];
      o4 += p * g2_rW[(2*DD + k)*DD + d] + p2 * g2_rW[(3*DD + k)*DD + d];
    }
    qT[(0*NB + b)*DD + d] = o1;
    qT[(1*NB + b)*DD + d] = o2;
    qT[(2*NB + b)*DD + d] = o3;
    qT[(3*NB + b)*DD + d] = o4;
  }
}

// tiled: 64 rows/block. h = tanh(X@pW + pb), then out1 = h@W1{a|b} (side by row<nvi),
// optionally out2 = h@W2a for A-side rows. 256 threads, 4x4 register tile.
__global__ __launch_bounds__(256, 2)
void k_proj_tf(const float* __restrict__ X, int nrows,
               const int* __restrict__ lim,
               const float* __restrict__ pW, const float* __restrict__ pb,
               const float* __restrict__ W1a, const float* __restrict__ W1b,
               const float* __restrict__ W2a,
               float* __restrict__ out1, float* __restrict__ out2) {
  __shared__ float Xt[DIN][68];
  __shared__ float Ht[DD][68];
  __shared__ float Wb[DD*DD];
  const int nvi  = lim ? lim[0] : 0x7fffffff;
  int nmax = lim ? lim[1] : nrows;
  if (nmax > nrows) nmax = nrows;
  const int row0 = blockIdx.x * 64;
  if (row0 >= nmax) return;
  const int tid = threadIdx.x;
  for (int i = tid; i < 64*DIN; i += 256) {
    int r = i / DIN, k = i - r*DIN;
    int row = row0 + r;
    Xt[k][r] = (row < nmax) ? X[row*DIN + k] : 0.f;
  }
  const int c0 = (tid & 15) << 2;
  const int r0 = (tid >> 4) << 2;
  float4 acc[4] = {{0,0,0,0},{0,0,0,0},{0,0,0,0},{0,0,0,0}};
  for (int kc = 0; kc < DIN; kc += DD) {
    int klen = min(DD, DIN - kc);
    if (kc > 0) __syncthreads();
    for (int i = tid; i < klen*DD; i += 256) Wb[i] = pW[kc*DD + i];
    __syncthreads();
    for (int k = 0; k < klen; ++k) {
      float4 x = *(const float4*)&Xt[kc + k][r0];
      float4 w = *(const float4*)&Wb[k*DD + c0];
      fma4x4(x, w, acc);
    }
  }
  const float4 pbv = *(const float4*)&pb[c0];
  #pragma unroll
  for (int i = 0; i < 4; ++i) {
    Ht[c0+0][r0+i] = tanhf(acc[i].x + pbv.x);
    Ht[c0+1][r0+i] = tanhf(acc[i].y + pbv.y);
    Ht[c0+2][r0+i] = tanhf(acc[i].z + pbv.z);
    Ht[c0+3][r0+i] = tanhf(acc[i].w + pbv.w);
  }
  __syncthreads();  // Wb reads + Ht writes complete
  const bool anyA = (row0 < nvi);
  const bool anyB = (row0 + 63 >= nvi);
  const bool hasW2 = (W2a != nullptr) && (out2 != nullptr);
  if (anyA) {
    for (int i = tid; i < DD*DD; i += 256) Wb[i] = W1a[i];
    __syncthreads();
    float4 a1[4] = {{0,0,0,0},{0,0,0,0},{0,0,0,0},{0,0,0,0}};
    for (int k = 0; k < DD; ++k) {
      float4 x = *(const float4*)&Ht[k][r0];
      float4 w = *(const float4*)&Wb[k*DD + c0];
      fma4x4(x, w, a1);
    }
    #pragma unroll
    for (int i = 0; i < 4; ++i) {
      int row = row0 + r0 + i;
      if (row < nvi && row < nmax) *(float4*)&out1[row*DD + c0] = a1[i];
    }
    if (hasW2) {
      __syncthreads();
      for (int i = tid; i < DD*DD; i += 256) Wb[i] = W2a[i];
      __syncthreads();
      float4 a2[4] = {{0,0,0,0},{0,0,0,0},{0,0,0,0},{0,0,0,0}};
      for (int k = 0; k < DD; ++k) {
        float4 x = *(const float4*)&Ht[k][r0];
        float4 w = *(const float4*)&Wb[k*DD + c0];
        fma4x4(x, w, a2);
      }
      #pragma unroll
      for (int i = 0; i < 4; ++i) {
        int row = row0 + r0 + i;
        if (row < nvi && row < nmax) *(float4*)&out2[row*DD + c0] = a2[i];
      }
    }
  }
  if (anyB) {
    __syncthreads();
    for (int i = tid; i < DD*DD; i += 256) Wb[i] = W1b[i];
    __syncthreads();
    float4 b1[4] = {{0,0,0,0},{0,0,0,0},{0,0,0,0},{0,0,0,0}};
    for (int k = 0; k < DD; ++k) {
      float4 x = *(const float4*)&Ht[k][r0];
      float4 w = *(const float4*)&Wb[k*DD + c0];
      fma4x4(x, w, b1);
    }
    #pragma unroll
    for (int i = 0; i < 4; ++i) {
      int row = row0 + r0 + i;
      if (row >= nvi && row < nmax) *(float4*)&out1[row*DD + c0] = b1[i];
    }
  }
}

// 64 edges/block: build l,r (leaky pre-acts) in LDS, z = l@cW^T via tiled GEMM,
// logit = sum_k r*z + l.cb, accumulated over g1,g2 into lg[]
__global__ __launch_bounds__(256, 2)
void k_edges(const int* __restrict__ edges,
             const float* __restrict__ TA, const float* __restrict__ TA2,
             const float* __restrict__ HU2,
             const float* __restrict__ rT, const float* __restrict__ qT,
             const float* __restrict__ cW1, const float* __restrict__ cb1,
             const float* __restrict__ cW2, const float* __restrict__ cb2,
             float* __restrict__ logits) {
  __shared__ float Lt[DD][68];
  __shared__ float Rt[DD][68];
  __shared__ float Wt[DD*68];
  __shared__ float lg[64];
  __shared__ int   se[64*8];
  const int tid = threadIdx.x;
  const int e0  = blockIdx.x * 64;
  const int ecnt = min(64, NE - e0);
  for (int i = tid; i < 64*8; i += 256) se[i] = (i < ecnt*8) ? edges[e0*8 + i] : 0;
  if (tid < 64) lg[tid] = 0.f;
  __syncthreads();
  const int e   = tid >> 2;
  const int d0  = (tid & 3) * 16;
  const int rel = se[e*8 + 3];
  const int eg  = se[e*8 + 0];
  const int li  = se[e*8 + 6];
  const int ee0 = (tid & 15) << 2;
  const int k0  = (tid >> 4) << 2;
  for (int g = 0; g < 2; ++g) {
    const float* Lb = g ? TA2 : TA;
    const float* Rb = g ? HU2 : TA;
    const float* rL = rT + (g ? 2*NR*DD : 0);
    const float* rR = rT + (g ? 3*NR*DD : 1*NR*DD);
    const float* qL = qT + (g ? 2*NB*DD : 0);
    const float* qR = qT + (g ? 3*NB*DD : 1*NB*DD);
    const float* cW = g ? cW2 : cW1;
    const float* cb = g ? cb2 : cb1;
    const int ri = g ? se[e*8 + 2] : se[e*8 + 7];
    float cbp = 0.f;
    #pragma unroll
    for (int di = 0; di < 4; ++di) {
      const int d = d0 + 4*di;
      float4 l = *(const float4*)&Lb[li*DD + d];
      float4 t = *(const float4*)&rL[rel*DD + d];
      float4 u = *(const float4*)&qL[eg*DD + d];
      l.x += t.x + u.x; l.y += t.y + u.y; l.z += t.z + u.z; l.w += t.w + u.w;
      l = leaky4(l);
      Lt[d+0][e] = l.x; Lt[d+1][e] = l.y; Lt[d+2][e] = l.z; Lt[d+3][e] = l.w;
      float4 c = *(const float4*)&cb[d];
      cbp += l.x*c.x + l.y*c.y + l.z*c.z + l.w*c.w;
      float4 r = *(const float4*)&Rb[ri*DD + d];
      t = *(const float4*)&rR[rel*DD + d];
      u = *(const float4*)&qR[eg*DD + d];
      r.x += t.x + u.x; r.y += t.y + u.y; r.z += t.z + u.z; r.w += t.w + u.w;
      r = leaky4(r);
      Rt[d+0][e] = r.x; Rt[d+1][e] = r.y; Rt[d+2][e] = r.z; Rt[d+3][e] = r.w;
    }
    atomicAdd(&lg[e], cbp);
    for (int i = tid; i < DD*DD; i += 256) {
      int k = i >> 6, d = i & 63;
      Wt[d*68 + k] = cW[i];   // transposed: Wt[d][k] = cW[k][d]
    }
    __syncthreads();
    float4 z[4] = {{0,0,0,0},{0,0,0,0},{0,0,0,0},{0,0,0,0}};
    for (int d = 0; d < DD; ++d) {
      float4 x = *(const float4*)&Lt[d][ee0];
      float4 w = *(const float4*)&Wt[d*68 + k0];
      fma4x4(x, w, z);  // z[edge].j over k
    }
    {
      float4 r0v = *(const float4*)&Rt[k0+0][ee0];
      float4 r1v = *(const float4*)&Rt[k0+1][ee0];
      float4 r2v = *(const float4*)&Rt[k0+2][ee0];
      float4 r3v = *(const float4*)&Rt[k0+3][ee0];
      float p0 = z[0].x*r0v.x + z[0].y*r1v.x + z[0].z*r2v.x + z[0].w*r3v.x;
      float p1 = z[1].x*r0v.y + z[1].y*r1v.y + z[1].z*r2v.y + z[1].w*r3v.y;
      float p2 = z[2].x*r0v.z + z[2].y*r1v.z + z[2].z*r2v.z + z[2].w*r3v.z;
      float p3 = z[3].x*r0v.w + z[3].y*r1v.w + z[3].z*r2v.w + z[3].w*r3v.w;
      atomicAdd(&lg[ee0+0], p0);
      atomicAdd(&lg[ee0+1], p1);
      atomicAdd(&lg[ee0+2], p2);
      atomicAdd(&lg[ee0+3], p3);
    }
    __syncthreads();
  }
  if (tid < ecnt) logits[e0 + tid] = lg[tid];
}

__global__ void k_softmax(const int* __restrict__ edges, const float* __restrict__ logits,
                          const float* __restrict__ na, float* __restrict__ out) {
  int e = blockIdx.x * blockDim.x + threadIdx.x;
  if (e >= NE) return;
  int seg = edges[e*8 + 4];
  if (e > 0 && edges[(e-1)*8 + 4] == seg) return;  // not a segment head
  int j = e;
  float m = -1e30f;
  while (j < NE && edges[j*8 + 4] == seg) { m = fmaxf(m, logits[j]); ++j; }
  float s = 0.f;
  for (int t = e; t < j; ++t) s += expf(logits[t] - m);
  int eg = edges[e*8 + 0], vi = edges[e*8 + 1];
  float scale = na[eg*NN + vi] / s;
  for (int t = e; t < j; ++t) {
    int vj = edges[t*8 + 2];
    __hip_atomic_fetch_add(&out[eg*NN + vj], expf(logits[t] - m) * scale,
                           __ATOMIC_RELAXED, __HIP_MEMORY_SCOPE_AGENT);
  }
}

__global__ void k_rowsum(const float* __restrict__ out, float* __restrict__ bsum) {
  int b = blockIdx.y;
  float s = 0.f;
  for (int n = blockIdx.x * blockDim.x + threadIdx.x; n < NN; n += gridDim.x * blockDim.x)
    s += out[b*NN + n];
  for (int off = 32; off > 0; off >>= 1) s += __shfl_down(s, off);
  if ((threadIdx.x & 63) == 0)
    __hip_atomic_fetch_add(&bsum[b], s, __ATOMIC_RELAXED, __HIP_MEMORY_SCOPE_AGENT);
}

__global__ void k_div(float* __restrict__ out, const float* __restrict__ bsum) {
  int i = blockIdx.x * blockDim.x + threadIdx.x;
  if (i < NB*NN) out[i] /= bsum[i / NN];
}

extern "C" void kernel_launch(void* const* d_in, const int* in_sizes, int n_in,
                              void* d_out, int out_size, void* d_ws, size_t ws_size,
                              hipStream_t stream) {
  (void)in_sizes; (void)n_in; (void)out_size; (void)ws_size;
  const float* na     = (const float*)d_in[0];
  const int*   edges  = (const int*)  d_in[1];
  const float* huncon = (const float*)d_in[2];
  const float* hcon   = (const float*)d_in[3];
  const float* rtab   = (const float*)d_in[4];
  const float* qh     = (const float*)d_in[5];
  const float* qr     = (const float*)d_in[6];
  const float* pW     = (const float*)d_in[7];
  const float* pb     = (const float*)d_in[8];
  const float* g1_lW  = (const float*)d_in[9];
  const float* g1_lb  = (const float*)d_in[10];
  const float* g1_rW  = (const float*)d_in[11];
  const float* g1_rb  = (const float*)d_in[12];
  const float* g1_cW  = (const float*)d_in[13];
  const float* g1_cb  = (const float*)d_in[14];
  const float* g2_lW  = (const float*)d_in[15];
  const float* g2_lb  = (const float*)d_in[16];
  const float* g2_rW  = (const float*)d_in[17];
  const float* g2_rb  = (const float*)d_in[18];
  const float* g2_cW  = (const float*)d_in[19];
  const float* g2_cb  = (const float*)d_in[20];
  float* out  = (float*)d_out;
  float* ws   = (float*)d_ws;
  int*   wsI  = (int*)d_ws;
  float* bsum = ws + 16;
  float* TA   = ws + TA_OFF;
  float* TA2  = ws + TA2_OFF;
  float* HU2  = ws + HU2_OFF;
  float* rT   = ws + RT_OFF;
  float* qT   = ws + QT_OFF;
  float* lgp  = ws + LG_OFF;

  hipMemsetAsync(d_out, 0, (size_t)NB*NN*sizeof(float), stream);
  k_init<<<1, 64, 0, stream>>>(wsI, bsum);
  k_limits<<<(NE + 255)/256, 256, 0, stream>>>(edges, wsI);
  k_tables<<<NR + NB, 64, 0, stream>>>(rtab, qh, qr, pW, pb,
                                       g1_lW, g1_lb, g1_rW, g1_rb,
                                       g2_lW, g2_lb, g2_rW, g2_rb, rT, qT);
  // node stage: HU2[n] = proj(hidden_uncon[n]) @ g2_rW[0:64]
  k_proj_tf<<<(NN + 63)/64, 256, 0, stream>>>(huncon, NN, nullptr, pW, pb,
                                              g2_rW, nullptr, nullptr, HU2, nullptr);
  // row stage: TA[m] = proj(hidden_con[m]) @ (m<nvi ? g1_lW[0:64] : g1_rW[0:64]);
  //            TA2[m] = proj(...) @ g2_lW[0:64] for m<nvi
  k_proj_tf<<<(NM + 63)/64, 256, 0, stream>>>(hcon, NM, wsI, pW, pb,
                                              g1_lW, g1_rW, g2_lW, TA, TA2);
  k_edges<<<(NE + 63)/64, 256, 0, stream>>>(edges, TA, TA2, HU2, rT, qT,
                                            g1_cW, g1_cb, g2_cW, g2_cb, lgp);
  k_softmax<<<(NE + 255)/256, 256, 0, stream>>>(edges, lgp, na, out);
  k_rowsum<<<dim3(32, 16), 256, 0, stream>>>(out, bsum);
  k_div<<<(NB*NN + 255)/256, 256, 0, stream>>>(out, bsum);
}

// Round 2
// 967.048 us; speedup vs baseline: 2.1951x; 2.1951x over previous
//
#include <hip/hip_runtime.h>

#define DIN 100
#define DD  64
#define NE  250000
#define NB  16
#define NN  50000
#define NR  500
#define NM  500000
#define NH  (NM + NN)

// workspace layout (float offsets). H doubles as TA (rows<nmax, in-place)
// and HU2 (rows >= NM, in-place).
#define H_OFF    64
#define TA2_OFF  (H_OFF + NH*DD)
#define RT_OFF   (TA2_OFF + NE*DD)
#define QT_OFF   (RT_OFF + 4*NR*DD)
#define LG_OFF   (QT_OFF + 4*NB*DD)

// k_tf grid segmentation
#define PA 480
#define PB 240
#define PC 48

__device__ __forceinline__ void fma4x4(const float4 x, const float4 w, float4 acc[4]) {
  acc[0].x += x.x*w.x; acc[0].y += x.x*w.y; acc[0].z += x.x*w.z; acc[0].w += x.x*w.w;
  acc[1].x += x.y*w.x; acc[1].y += x.y*w.y; acc[1].z += x.y*w.z; acc[1].w += x.y*w.w;
  acc[2].x += x.z*w.x; acc[2].y += x.z*w.y; acc[2].z += x.z*w.z; acc[2].w += x.z*w.w;
  acc[3].x += x.w*w.x; acc[3].y += x.w*w.y; acc[3].z += x.w*w.z; acc[3].w += x.w*w.w;
}

__device__ __forceinline__ float4 leaky4(float4 v) {
  v.x = v.x > 0.f ? v.x : 0.2f*v.x;
  v.y = v.y > 0.f ? v.y : 0.2f*v.y;
  v.z = v.z > 0.f ? v.z : 0.2f*v.z;
  v.w = v.w > 0.f ? v.w : 0.2f*v.w;
  return v;
}

__global__ void k_init(int* wsI, float* bsum) {
  if (threadIdx.x == 0) { wsI[0] = 0x7fffffff; wsI[1] = 0; }
  if (threadIdx.x < NB) bsum[threadIdx.x] = 0.f;
}

__global__ void k_limits(const int* __restrict__ edges, int* __restrict__ wsI) {
  int i = blockIdx.x * blockDim.x + threadIdx.x;
  int mn = 0x7fffffff, mx = -1;
  if (i < NE) { int v = edges[i*8 + 7]; mn = v; mx = v; }
  for (int off = 32; off > 0; off >>= 1) {
    mn = min(mn, __shfl_down(mn, off));
    mx = max(mx, __shfl_down(mx, off));
  }
  if ((threadIdx.x & 63) == 0) {
    atomicMin(&wsI[0], mn);
    atomicMax(&wsI[1], mx + 1);
  }
}

// one 64-thread block per (rel row | batch row): builds per-rel / per-batch tables
__global__ void k_tables(const float* __restrict__ rtab,
                         const float* __restrict__ qh, const float* __restrict__ qr,
                         const float* __restrict__ pW, const float* __restrict__ pb,
                         const float* __restrict__ g1_lW, const float* __restrict__ g1_lb,
                         const float* __restrict__ g1_rW, const float* __restrict__ g1_rb,
                         const float* __restrict__ g2_lW, const float* __restrict__ g2_lb,
                         const float* __restrict__ g2_rW, const float* __restrict__ g2_rb,
                         float* __restrict__ rT, float* __restrict__ qT) {
  __shared__ float xs[DIN], xs2[DIN], ps[DD], ps2[DD];
  const int d = threadIdx.x;
  const int blk = blockIdx.x;
  if (blk < NR) {
    for (int k = d; k < DIN; k += 64) xs[k] = rtab[blk*DIN + k];
    __syncthreads();
    float a = pb[d];
    for (int k = 0; k < DIN; ++k) a += xs[k] * pW[k*DD + d];
    ps[d] = tanhf(a);
    __syncthreads();
    float o1 = 0.f, o2 = 0.f, o3 = 0.f, o4 = 0.f;
    for (int k = 0; k < DD; ++k) {
      float p = ps[k];
      o1 += p * g1_lW[(DD + k)*DD + d];
      o2 += p * g1_rW[(DD + k)*DD + d];
      o3 += p * g2_lW[(DD + k)*DD + d];
      o4 += p * g2_rW[(DD + k)*DD + d];
    }
    rT[(0*NR + blk)*DD + d] = o1;
    rT[(1*NR + blk)*DD + d] = o2;
    rT[(2*NR + blk)*DD + d] = o3;
    rT[(3*NR + blk)*DD + d] = o4;
  } else {
    const int b = blk - NR;
    for (int k = d; k < DIN; k += 64) { xs[k] = qh[b*DIN + k]; xs2[k] = qr[b*DIN + k]; }
    __syncthreads();
    float a = pb[d], a2 = pb[d];
    for (int k = 0; k < DIN; ++k) { a += xs[k]*pW[k*DD + d]; a2 += xs2[k]*pW[k*DD + d]; }
    ps[d] = tanhf(a); ps2[d] = tanhf(a2);
    __syncthreads();
    float o1 = g1_lb[d], o2 = g1_rb[d], o3 = g2_lb[d], o4 = g2_rb[d];
    for (int k = 0; k < DD; ++k) {
      float p = ps[k], p2 = ps2[k];
      o1 += p * g1_lW[(2*DD + k)*DD + d] + p2 * g1_lW[(3*DD + k)*DD + d];
      o2 += p * g1_rW[(2*DD + k)*DD + d] + p2 * g1_rW[(3*DD + k)*DD + d];
      o3 += p * g2_lW[(2*DD + k)*DD + d] + p2 * g2_lW[(3*DD + k)*DD + d];
      o4 += p * g2_rW[(2*DD + k)*DD + d] + p2 * g2_rW[(3*DD + k)*DD + d];
    }
    qT[(0*NB + b)*DD + d] = o1;
    qT[(1*NB + b)*DD + d] = o2;
    qT[(2*NB + b)*DD + d] = o3;
    qT[(3*NB + b)*DD + d] = o4;
  }
}

// persistent proj: H[row] = tanh(X[row] @ pW + pb), X = hcon rows then huncon rows.
// pW resident in LDS; 2 barriers/tile. 3 blocks/CU (52.8 KB LDS).
__global__ __launch_bounds__(256, 3)
void k_proj(const float* __restrict__ hcon, const float* __restrict__ huncon,
            const float* __restrict__ pW, const float* __restrict__ pb,
            const int* __restrict__ lim, float* __restrict__ H) {
  __shared__ __align__(16) float pWs[DIN*DD];
  __shared__ __align__(16) float Xt[DIN][68];
  const int tid = threadIdx.x;
  for (int i = tid; i < DIN*DD; i += 256) pWs[i] = pW[i];
  const int c0 = (tid & 15) << 2;
  const int r0 = (tid >> 4) << 2;
  const float4 pbv = *(const float4*)&pb[c0];
  const int nmax = lim[1];
  const int t_lo = (nmax + 63) >> 6;               // con tiles [0, t_lo)
  const int NT   = t_lo + (NN + 63) / 64;          // + 782 huncon tiles
  __syncthreads();
  for (int t = blockIdx.x; t < NT; t += gridDim.x) {
    const int row0 = (t < t_lo) ? t*64 : NM + (t - t_lo)*64;
    for (int i = tid; i < 64*DIN; i += 256) {
      int r = i / DIN, k = i - r*DIN;
      int row = row0 + r;
      float v = 0.f;
      if (row < NH) v = (row < NM) ? hcon[row*DIN + k] : huncon[(row - NM)*DIN + k];
      Xt[k][r] = v;
    }
    __syncthreads();
    float4 acc[4] = {{0,0,0,0},{0,0,0,0},{0,0,0,0},{0,0,0,0}};
    for (int k = 0; k < DIN; ++k) {
      float4 x = *(const float4*)&Xt[k][r0];
      float4 w = *(const float4*)&pWs[k*DD + c0];
      fma4x4(x, w, acc);
    }
    #pragma unroll
    for (int i = 0; i < 4; ++i) {
      int row = row0 + r0 + i;
      if (row < NH) {
        float4 o;
        o.x = tanhf(acc[i].x + pbv.x);
        o.y = tanhf(acc[i].y + pbv.y);
        o.z = tanhf(acc[i].z + pbv.z);
        o.w = tanhf(acc[i].w + pbv.w);
        *(float4*)&H[row*DD + c0] = o;
      }
    }
    __syncthreads();
  }
}

// persistent transform, 3 pools by weight set; in-place over H.
// pool 0: rows<nvi : TA=H@W1a (in place), TA2=H@W2a
// pool 1: rows in [nvi,nmax): TA=H@W1b (in place)
// pool 2: huncon rows: HU2=H@g2_rW (in place)
__global__ __launch_bounds__(256, 3)
void k_tf(const float* __restrict__ g1_lW, const float* __restrict__ g1_rW,
          const float* __restrict__ g2_lW, const float* __restrict__ g2_rW,
          const int* __restrict__ lim,
          float* __restrict__ H, float* __restrict__ TA2) {
  __shared__ __align__(16) float Ws0[DD*DD];
  __shared__ __align__(16) float Ws1[DD*DD];
  __shared__ __align__(16) float Ht[DD][68];
  const int tid = threadIdx.x;
  const int nvi  = lim[0];
  const int nmax = lim[1];
  int pool, pbase, pgrid;
  if (blockIdx.x < PA)           { pool = 0; pbase = blockIdx.x;           pgrid = PA; }
  else if (blockIdx.x < PA + PB) { pool = 1; pbase = blockIdx.x - PA;      pgrid = PB; }
  else                           { pool = 2; pbase = blockIdx.x - PA - PB; pgrid = PC; }
  if (pool == 0) {
    for (int i = tid; i < DD*DD; i += 256) { Ws0[i] = g1_lW[i]; Ws1[i] = g2_lW[i]; }
  } else if (pool == 1) {
    for (int i = tid; i < DD*DD; i += 256) Ws0[i] = g1_rW[i];
  } else {
    for (int i = tid; i < DD*DD; i += 256) Ws0[i] = g2_rW[i];
  }
  int t_begin, t_count, row_base;
  if (pool == 0)      { t_begin = 0;        t_count = (nvi + 63) >> 6;                 row_base = 0;  }
  else if (pool == 1) { t_begin = nvi >> 6; t_count = ((nmax + 63) >> 6) - (nvi >> 6); row_base = 0;  }
  else                { t_begin = 0;        t_count = (NN + 63) >> 6;                  row_base = NM; }
  const int c0 = (tid & 15) << 2;
  const int r0 = (tid >> 4) << 2;
  __syncthreads();
  for (int tt = pbase; tt < t_count; tt += pgrid) {
    const int row0 = row_base + (t_begin + tt)*64;
    for (int i = tid; i < 64*DD; i += 256) {
      int d = i & 63, r = i >> 6;
      int row = row0 + r;
      Ht[d][r] = (row < NH) ? H[row*DD + d] : 0.f;
    }
    __syncthreads();
    float4 a0[4] = {{0,0,0,0},{0,0,0,0},{0,0,0,0},{0,0,0,0}};
    for (int k = 0; k < DD; ++k) {
      float4 x = *(const float4*)&Ht[k][r0];
      float4 w = *(const float4*)&Ws0[k*DD + c0];
      fma4x4(x, w, a0);
    }
    if (pool == 0) {
      float4 a1[4] = {{0,0,0,0},{0,0,0,0},{0,0,0,0},{0,0,0,0}};
      for (int k = 0; k < DD; ++k) {
        float4 x = *(const float4*)&Ht[k][r0];
        float4 w = *(const float4*)&Ws1[k*DD + c0];
        fma4x4(x, w, a1);
      }
      #pragma unroll
      for (int i = 0; i < 4; ++i) {
        int row = row0 + r0 + i;
        if (row < nvi) {
          *(float4*)&H[row*DD + c0]   = a0[i];
          *(float4*)&TA2[row*DD + c0] = a1[i];
        }
      }
    } else if (pool == 1) {
      #pragma unroll
      for (int i = 0; i < 4; ++i) {
        int row = row0 + r0 + i;
        if (row >= nvi && row < nmax) *(float4*)&H[row*DD + c0] = a0[i];
      }
    } else {
      #pragma unroll
      for (int i = 0; i < 4; ++i) {
        int row = row0 + r0 + i;
        if (row < NH) *(float4*)&H[row*DD + c0] = a0[i];
      }
    }
    __syncthreads();
  }
}

// persistent edge kernel: cW1/cW2 transposed + cb resident in LDS.
__global__ __launch_bounds__(256, 2)
void k_edges(const int* __restrict__ edges,
             const float* __restrict__ TA, const float* __restrict__ TA2,
             const float* __restrict__ HU2,
             const float* __restrict__ rT, const float* __restrict__ qT,
             const float* __restrict__ cW1, const float* __restrict__ cb1,
             const float* __restrict__ cW2, const float* __restrict__ cb2,
             float* __restrict__ logits) {
  __shared__ __align__(16) float Wt1s[DD*68];
  __shared__ __align__(16) float Wt2s[DD*68];
  __shared__ __align__(16) float Lt[DD][68];
  __shared__ __align__(16) float Rt[DD][68];
  __shared__ __align__(16) float4 cbs4[2][16];
  __shared__ float lg[64];
  __shared__ int   se[64*8];
  const int tid = threadIdx.x;
  for (int i = tid; i < DD*DD; i += 256) {
    int k = i >> 6, d = i & 63;
    Wt1s[d*68 + k] = cW1[i];   // Wt[d][k] = cW[k][d]
    Wt2s[d*68 + k] = cW2[i];
  }
  if (tid < 16) {
    cbs4[0][tid] = *(const float4*)&cb1[tid*4];
    cbs4[1][tid] = *(const float4*)&cb2[tid*4];
  }
  const int e   = tid >> 2;
  const int d0  = (tid & 3) * 16;
  const int ee0 = (tid & 15) << 2;
  const int k0  = (tid >> 4) << 2;
  __syncthreads();
  const int NT = (NE + 63) / 64;
  for (int tile = blockIdx.x; tile < NT; tile += gridDim.x) {
    const int e0 = tile * 64;
    const int ecnt = min(64, NE - e0);
    for (int i = tid; i < 64*8; i += 256) se[i] = (i < ecnt*8) ? edges[e0*8 + i] : 0;
    if (tid < 64) lg[tid] = 0.f;
    __syncthreads();
    const int rel = se[e*8 + 3];
    const int eg  = se[e*8 + 0];
    const int li  = se[e*8 + 6];
    for (int g = 0; g < 2; ++g) {
      const float* Lb = g ? TA2 : TA;
      const float* Rb = g ? HU2 : TA;
      const float* rL = rT + (g ? 2*NR*DD : 0);
      const float* rR = rT + (g ? 3*NR*DD : 1*NR*DD);
      const float* qL = qT + (g ? 2*NB*DD : 0);
      const float* qR = qT + (g ? 3*NB*DD : 1*NB*DD);
      const float* Wts = g ? Wt2s : Wt1s;
      const int ri = g ? se[e*8 + 2] : se[e*8 + 7];
      float cbp = 0.f;
      #pragma unroll
      for (int di = 0; di < 4; ++di) {
        const int d = d0 + 4*di;
        float4 l = *(const float4*)&Lb[li*DD + d];
        float4 t = *(const float4*)&rL[rel*DD + d];
        float4 u = *(const float4*)&qL[eg*DD + d];
        l.x += t.x + u.x; l.y += t.y + u.y; l.z += t.z + u.z; l.w += t.w + u.w;
        l = leaky4(l);
        Lt[d+0][e] = l.x; Lt[d+1][e] = l.y; Lt[d+2][e] = l.z; Lt[d+3][e] = l.w;
        float4 c = cbs4[g][d >> 2];
        cbp += l.x*c.x + l.y*c.y + l.z*c.z + l.w*c.w;
        float4 r = *(const float4*)&Rb[ri*DD + d];
        t = *(const float4*)&rR[rel*DD + d];
        u = *(const float4*)&qR[eg*DD + d];
        r.x += t.x + u.x; r.y += t.y + u.y; r.z += t.z + u.z; r.w += t.w + u.w;
        r = leaky4(r);
        Rt[d+0][e] = r.x; Rt[d+1][e] = r.y; Rt[d+2][e] = r.z; Rt[d+3][e] = r.w;
      }
      atomicAdd(&lg[e], cbp);
      __syncthreads();
      float4 z[4] = {{0,0,0,0},{0,0,0,0},{0,0,0,0},{0,0,0,0}};
      for (int d = 0; d < DD; ++d) {
        float4 x = *(const float4*)&Lt[d][ee0];
        float4 w = *(const float4*)&Wts[d*68 + k0];
        fma4x4(x, w, z);
      }
      {
        float4 r0v = *(const float4*)&Rt[k0+0][ee0];
        float4 r1v = *(const float4*)&Rt[k0+1][ee0];
        float4 r2v = *(const float4*)&Rt[k0+2][ee0];
        float4 r3v = *(const float4*)&Rt[k0+3][ee0];
        float p0 = z[0].x*r0v.x + z[0].y*r1v.x + z[0].z*r2v.x + z[0].w*r3v.x;
        float p1 = z[1].x*r0v.y + z[1].y*r1v.y + z[1].z*r2v.y + z[1].w*r3v.y;
        float p2 = z[2].x*r0v.z + z[2].y*r1v.z + z[2].z*r2v.z + z[2].w*r3v.z;
        float p3 = z[3].x*r0v.w + z[3].y*r1v.w + z[3].z*r2v.w + z[3].w*r3v.w;
        atomicAdd(&lg[ee0+0], p0);
        atomicAdd(&lg[ee0+1], p1);
        atomicAdd(&lg[ee0+2], p2);
        atomicAdd(&lg[ee0+3], p3);
      }
      __syncthreads();
    }
    if (tid < ecnt) logits[e0 + tid] = lg[tid];
    __syncthreads();
  }
}

__global__ void k_softmax(const int* __restrict__ edges, const float* __restrict__ logits,
                          const float* __restrict__ na, float* __restrict__ out) {
  int e = blockIdx.x * blockDim.x + threadIdx.x;
  if (e >= NE) return;
  int seg = edges[e*8 + 4];
  if (e > 0 && edges[(e-1)*8 + 4] == seg) return;  // not a segment head
  int j = e;
  float m = -1e30f;
  while (j < NE && edges[j*8 + 4] == seg) { m = fmaxf(m, logits[j]); ++j; }
  float s = 0.f;
  for (int t = e; t < j; ++t) s += expf(logits[t] - m);
  int eg = edges[e*8 + 0], vi = edges[e*8 + 1];
  float scale = na[eg*NN + vi] / s;
  for (int t = e; t < j; ++t) {
    int vj = edges[t*8 + 2];
    __hip_atomic_fetch_add(&out[eg*NN + vj], expf(logits[t] - m) * scale,
                           __ATOMIC_RELAXED, __HIP_MEMORY_SCOPE_AGENT);
  }
}

__global__ void k_rowsum(const float* __restrict__ out, float* __restrict__ bsum) {
  int b = blockIdx.y;
  float s = 0.f;
  for (int n = blockIdx.x * blockDim.x + threadIdx.x; n < NN; n += gridDim.x * blockDim.x)
    s += out[b*NN + n];
  for (int off = 32; off > 0; off >>= 1) s += __shfl_down(s, off);
  if ((threadIdx.x & 63) == 0)
    __hip_atomic_fetch_add(&bsum[b], s, __ATOMIC_RELAXED, __HIP_MEMORY_SCOPE_AGENT);
}

__global__ void k_div(float* __restrict__ out, const float* __restrict__ bsum) {
  int i = blockIdx.x * blockDim.x + threadIdx.x;
  if (i < NB*NN) out[i] /= bsum[i / NN];
}

extern "C" void kernel_launch(void* const* d_in, const int* in_sizes, int n_in,
                              void* d_out, int out_size, void* d_ws, size_t ws_size,
                              hipStream_t stream) {
  (void)in_sizes; (void)n_in; (void)out_size; (void)ws_size;
  const float* na     = (const float*)d_in[0];
  const int*   edges  = (const int*)  d_in[1];
  const float* huncon = (const float*)d_in[2];
  const float* hcon   = (const float*)d_in[3];
  const float* rtab   = (const float*)d_in[4];
  const float* qh     = (const float*)d_in[5];
  const float* qr     = (const float*)d_in[6];
  const float* pW     = (const float*)d_in[7];
  const float* pb     = (const float*)d_in[8];
  const float* g1_lW  = (const float*)d_in[9];
  const float* g1_lb  = (const float*)d_in[10];
  const float* g1_rW  = (const float*)d_in[11];
  const float* g1_rb  = (const float*)d_in[12];
  const float* g1_cW  = (const float*)d_in[13];
  const float* g1_cb  = (const float*)d_in[14];
  const float* g2_lW  = (const float*)d_in[15];
  const float* g2_lb  = (const float*)d_in[16];
  const float* g2_rW  = (const float*)d_in[17];
  const float* g2_rb  = (const float*)d_in[18];
  const float* g2_cW  = (const float*)d_in[19];
  const float* g2_cb  = (const float*)d_in[20];
  float* out  = (float*)d_out;
  float* ws   = (float*)d_ws;
  int*   wsI  = (int*)d_ws;
  float* bsum = ws + 16;
  float* H    = ws + H_OFF;            // TA in-place; HU2 = H + NM*DD
  float* TA2  = ws + TA2_OFF;
  float* rT   = ws + RT_OFF;
  float* qT   = ws + QT_OFF;
  float* lgp  = ws + LG_OFF;

  hipMemsetAsync(d_out, 0, (size_t)NB*NN*sizeof(float), stream);
  k_init<<<1, 64, 0, stream>>>(wsI, bsum);
  k_limits<<<(NE + 255)/256, 256, 0, stream>>>(edges, wsI);
  k_tables<<<NR + NB, 64, 0, stream>>>(rtab, qh, qr, pW, pb,
                                       g1_lW, g1_lb, g1_rW, g1_rb,
                                       g2_lW, g2_lb, g2_rW, g2_rb, rT, qT);
  k_proj<<<768, 256, 0, stream>>>(hcon, huncon, pW, pb, wsI, H);
  k_tf<<<PA + PB + PC, 256, 0, stream>>>(g1_lW, g1_rW, g2_lW, g2_rW, wsI, H, TA2);
  k_edges<<<512, 256, 0, stream>>>(edges, H, TA2, H + NM*DD, rT, qT,
                                   g1_cW, g1_cb, g2_cW, g2_cb, lgp);
  k_softmax<<<(NE + 255)/256, 256, 0, stream>>>(edges, lgp, na, out);
  k_rowsum<<<dim3(32, 16), 256, 0, stream>>>(out, bsum);
  k_div<<<(NB*NN + 255)/256, 256, 0, stream>>>(out, bsum);
}

// Round 3
// 816.792 us; speedup vs baseline: 2.5990x; 1.1840x over previous
//
#include <hip/hip_runtime.h>

#define DIN 100
#define DD  64
#define NE  250000
#define NB  16
#define NN  50000
#define NR  500
#define NM  500000
#define NH  (NM + NN)

// workspace layout (float offsets). H doubles as TA (rows<nmax, in-place)
// and HU2 (rows >= NM, in-place).
#define H_OFF    64
#define TA2_OFF  (H_OFF + NH*DD)
#define RT_OFF   (TA2_OFF + NE*DD)
#define QT_OFF   (RT_OFF + 4*NR*DD)
#define LG_OFF   (QT_OFF + 4*NB*DD)

// k_tf grid segmentation (pool0 does 2 GEMMs -> 2:1:~1/6 work split)
#define PA 320
#define PB 160
#define PC 32

#define XT_STRIDE 260   // %32==4 -> 2-way (free) on tiled reads; 16B-aligned rows

__device__ __forceinline__ void fma4x4(const float4 x, const float4 w, float4 acc[4]) {
  acc[0].x += x.x*w.x; acc[0].y += x.x*w.y; acc[0].z += x.x*w.z; acc[0].w += x.x*w.w;
  acc[1].x += x.y*w.x; acc[1].y += x.y*w.y; acc[1].z += x.y*w.z; acc[1].w += x.y*w.w;
  acc[2].x += x.z*w.x; acc[2].y += x.z*w.y; acc[2].z += x.z*w.z; acc[2].w += x.z*w.w;
  acc[3].x += x.w*w.x; acc[3].y += x.w*w.y; acc[3].z += x.w*w.z; acc[3].w += x.w*w.w;
}

__device__ __forceinline__ float4 leaky4(float4 v) {
  v.x = v.x > 0.f ? v.x : 0.2f*v.x;
  v.y = v.y > 0.f ? v.y : 0.2f*v.y;
  v.z = v.z > 0.f ? v.z : 0.2f*v.z;
  v.w = v.w > 0.f ? v.w : 0.2f*v.w;
  return v;
}

__global__ void k_init(int* wsI, float* bsum) {
  if (threadIdx.x == 0) { wsI[0] = 0x7fffffff; wsI[1] = 0; }
  if (threadIdx.x < NB) bsum[threadIdx.x] = 0.f;
}

__global__ void k_limits(const int* __restrict__ edges, int* __restrict__ wsI) {
  int i = blockIdx.x * blockDim.x + threadIdx.x;
  int mn = 0x7fffffff, mx = -1;
  if (i < NE) { int v = edges[i*8 + 7]; mn = v; mx = v; }
  for (int off = 32; off > 0; off >>= 1) {
    mn = min(mn, __shfl_down(mn, off));
    mx = max(mx, __shfl_down(mx, off));
  }
  if ((threadIdx.x & 63) == 0) {
    atomicMin(&wsI[0], mn);
    atomicMax(&wsI[1], mx + 1);
  }
}

// one 64-thread block per (rel row | batch row): builds per-rel / per-batch tables
__global__ void k_tables(const float* __restrict__ rtab,
                         const float* __restrict__ qh, const float* __restrict__ qr,
                         const float* __restrict__ pW, const float* __restrict__ pb,
                         const float* __restrict__ g1_lW, const float* __restrict__ g1_lb,
                         const float* __restrict__ g1_rW, const float* __restrict__ g1_rb,
                         const float* __restrict__ g2_lW, const float* __restrict__ g2_lb,
                         const float* __restrict__ g2_rW, const float* __restrict__ g2_rb,
                         float* __restrict__ rT, float* __restrict__ qT) {
  __shared__ float xs[DIN], xs2[DIN], ps[DD], ps2[DD];
  const int d = threadIdx.x;
  const int blk = blockIdx.x;
  if (blk < NR) {
    for (int k = d; k < DIN; k += 64) xs[k] = rtab[blk*DIN + k];
    __syncthreads();
    float a = pb[d];
    for (int k = 0; k < DIN; ++k) a += xs[k] * pW[k*DD + d];
    ps[d] = tanhf(a);
    __syncthreads();
    float o1 = 0.f, o2 = 0.f, o3 = 0.f, o4 = 0.f;
    for (int k = 0; k < DD; ++k) {
      float p = ps[k];
      o1 += p * g1_lW[(DD + k)*DD + d];
      o2 += p * g1_rW[(DD + k)*DD + d];
      o3 += p * g2_lW[(DD + k)*DD + d];
      o4 += p * g2_rW[(DD + k)*DD + d];
    }
    rT[(0*NR + blk)*DD + d] = o1;
    rT[(1*NR + blk)*DD + d] = o2;
    rT[(2*NR + blk)*DD + d] = o3;
    rT[(3*NR + blk)*DD + d] = o4;
  } else {
    const int b = blk - NR;
    for (int k = d; k < DIN; k += 64) { xs[k] = qh[b*DIN + k]; xs2[k] = qr[b*DIN + k]; }
    __syncthreads();
    float a = pb[d], a2 = pb[d];
    for (int k = 0; k < DIN; ++k) { a += xs[k]*pW[k*DD + d]; a2 += xs2[k]*pW[k*DD + d]; }
    ps[d] = tanhf(a); ps2[d] = tanhf(a2);
    __syncthreads();
    float o1 = g1_lb[d], o2 = g1_rb[d], o3 = g2_lb[d], o4 = g2_rb[d];
    for (int k = 0; k < DD; ++k) {
      float p = ps[k], p2 = ps2[k];
      o1 += p * g1_lW[(2*DD + k)*DD + d] + p2 * g1_lW[(3*DD + k)*DD + d];
      o2 += p * g1_rW[(2*DD + k)*DD + d] + p2 * g1_rW[(3*DD + k)*DD + d];
      o3 += p * g2_lW[(2*DD + k)*DD + d] + p2 * g2_lW[(3*DD + k)*DD + d];
      o4 += p * g2_rW[(2*DD + k)*DD + d] + p2 * g2_rW[(3*DD + k)*DD + d];
    }
    qT[(0*NB + b)*DD + d] = o1;
    qT[(1*NB + b)*DD + d] = o2;
    qT[(2*NB + b)*DD + d] = o3;
    qT[(3*NB + b)*DD + d] = o4;
  }
}

// persistent proj, 256-row tiles, 8x8 register tile per thread.
// 4 ds_read_b128 feed 64 FMA (1.5:1 LDS:FMA vs 3:1 for 4x4).
// LDS 79.7 KB -> 2 blocks/CU.
__global__ __launch_bounds__(256, 2)
void k_proj(const float* __restrict__ hcon, const float* __restrict__ huncon,
            const float* __restrict__ pW, const float* __restrict__ pb,
            const int* __restrict__ lim, float* __restrict__ H) {
  __shared__ __align__(16) float pWs[DIN*DD];        // 25.6 KB
  __shared__ __align__(16) float Xt[52][XT_STRIDE];  // 54.1 KB
  const int tid = threadIdx.x;
  for (int i = tid; i < DIN*DD; i += 256) pWs[i] = pW[i];
  const int tc = tid & 7, tr = tid >> 3;
  const int c0 = tc << 3;
  const float4 pb0 = *(const float4*)&pb[c0];
  const float4 pb1 = *(const float4*)&pb[c0 + 4];
  const int nmax = lim[1];
  const int t_lo = (nmax + 255) >> 8;
  const int NT   = t_lo + ((NN + 255) >> 8);
  __syncthreads();
  for (int t = blockIdx.x; t < NT; t += gridDim.x) {
    const int row0 = (t < t_lo) ? (t << 8) : (NM + ((t - t_lo) << 8));
    const int myrow = row0 + tid;                     // staging: one row per thread
    const float* src = nullptr;
    if (myrow < NH) src = (myrow < NM) ? &hcon[myrow*DIN] : &huncon[(myrow - NM)*DIN];
    float4 acc[2][2][4];
    #pragma unroll
    for (int a = 0; a < 2; ++a)
      #pragma unroll
      for (int b = 0; b < 2; ++b)
        #pragma unroll
        for (int i = 0; i < 4; ++i) acc[a][b][i] = make_float4(0.f,0.f,0.f,0.f);
    #pragma unroll
    for (int chunk = 0; chunk < 2; ++chunk) {
      const int kb = chunk ? 48 : 0;
      const int klen = chunk ? 52 : 48;
      __syncthreads();
      if (src) {
        for (int j = 0; j < klen; j += 4) {
          float4 v = *(const float4*)&src[kb + j];
          Xt[j+0][tid] = v.x; Xt[j+1][tid] = v.y; Xt[j+2][tid] = v.z; Xt[j+3][tid] = v.w;
        }
      }
      __syncthreads();
      for (int k = 0; k < klen; ++k) {
        float4 x0 = *(const float4*)&Xt[k][tr*8];
        float4 x1 = *(const float4*)&Xt[k][tr*8 + 4];
        float4 w0 = *(const float4*)&pWs[(kb + k)*DD + c0];
        float4 w1 = *(const float4*)&pWs[(kb + k)*DD + c0 + 4];
        fma4x4(x0, w0, acc[0][0]); fma4x4(x0, w1, acc[0][1]);
        fma4x4(x1, w0, acc[1][0]); fma4x4(x1, w1, acc[1][1]);
      }
    }
    #pragma unroll
    for (int a = 0; a < 2; ++a)
      #pragma unroll
      for (int i = 0; i < 4; ++i) {
        int row = row0 + tr*8 + a*4 + i;
        if (row < NH) {
          float4 o0, o1;
          o0.x = tanhf(acc[a][0][i].x + pb0.x);
          o0.y = tanhf(acc[a][0][i].y + pb0.y);
          o0.z = tanhf(acc[a][0][i].z + pb0.z);
          o0.w = tanhf(acc[a][0][i].w + pb0.w);
          o1.x = tanhf(acc[a][1][i].x + pb1.x);
          o1.y = tanhf(acc[a][1][i].y + pb1.y);
          o1.z = tanhf(acc[a][1][i].z + pb1.z);
          o1.w = tanhf(acc[a][1][i].w + pb1.w);
          *(float4*)&H[row*DD + c0]     = o0;
          *(float4*)&H[row*DD + c0 + 4] = o1;
        }
      }
  }
}

// persistent transform, 256-row tiles, 8x8 register tile, weights resident.
// pool 0: rows<nvi : TA=H@W1a (in place), TA2=H@W2a
// pool 1: rows in [nvi,nmax): TA=H@W1b (in place)
// pool 2: huncon rows: HU2=H@g2_rW (in place)
// Transform is row-local, so in-place overwrite of H is race-free.
__global__ __launch_bounds__(256, 2)
void k_tf(const float* __restrict__ g1_lW, const float* __restrict__ g1_rW,
          const float* __restrict__ g2_lW, const float* __restrict__ g2_rW,
          const int* __restrict__ lim,
          float* __restrict__ H, float* __restrict__ TA2) {
  __shared__ __align__(16) float Ws0[DD*DD];         // 16 KB
  __shared__ __align__(16) float Ws1[DD*DD];         // 16 KB
  __shared__ __align__(16) float Ht[32][XT_STRIDE];  // 33.3 KB
  const int tid = threadIdx.x;
  const int nvi  = lim[0];
  const int nmax = lim[1];
  int pool, pbase, pgrid;
  if (blockIdx.x < PA)           { pool = 0; pbase = blockIdx.x;           pgrid = PA; }
  else if (blockIdx.x < PA + PB) { pool = 1; pbase = blockIdx.x - PA;      pgrid = PB; }
  else                           { pool = 2; pbase = blockIdx.x - PA - PB; pgrid = PC; }
  if (pool == 0) {
    for (int i = tid; i < DD*DD; i += 256) { Ws0[i] = g1_lW[i]; Ws1[i] = g2_lW[i]; }
  } else if (pool == 1) {
    for (int i = tid; i < DD*DD; i += 256) Ws0[i] = g1_rW[i];
  } else {
    for (int i = tid; i < DD*DD; i += 256) Ws0[i] = g2_rW[i];
  }
  int t_begin, t_count, row_base;
  if (pool == 0)      { t_begin = 0;        t_count = (nvi + 255) >> 8;                 row_base = 0;  }
  else if (pool == 1) { t_begin = nvi >> 8; t_count = ((nmax + 255) >> 8) - (nvi >> 8); row_base = 0;  }
  else                { t_begin = 0;        t_count = (NN + 255) >> 8;                  row_base = NM; }
  const int tc = tid & 7, tr = tid >> 3;
  const int c0 = tc << 3;
  __syncthreads();
  for (int tt = pbase; tt < t_count; tt += pgrid) {
    const int row0 = row_base + ((t_begin + tt) << 8);
    const int myrow = row0 + tid;
    float4 a0[2][2][4], a1[2][2][4];
    #pragma unroll
    for (int a = 0; a < 2; ++a)
      #pragma unroll
      for (int b = 0; b < 2; ++b)
        #pragma unroll
        for (int i = 0; i < 4; ++i) {
          a0[a][b][i] = make_float4(0.f,0.f,0.f,0.f);
          a1[a][b][i] = make_float4(0.f,0.f,0.f,0.f);
        }
    #pragma unroll
    for (int chunk = 0; chunk < 2; ++chunk) {
      const int kb = chunk << 5;
      __syncthreads();
      if (myrow < NH) {
        const float* src = &H[myrow*DD + kb];
        #pragma unroll
        for (int j = 0; j < 32; j += 4) {
          float4 v = *(const float4*)&src[j];
          Ht[j+0][tid] = v.x; Ht[j+1][tid] = v.y; Ht[j+2][tid] = v.z; Ht[j+3][tid] = v.w;
        }
      }
      __syncthreads();
      if (pool == 0) {
        for (int k = 0; k < 32; ++k) {
          float4 x0 = *(const float4*)&Ht[k][tr*8];
          float4 x1 = *(const float4*)&Ht[k][tr*8 + 4];
          float4 w0 = *(const float4*)&Ws0[(kb + k)*DD + c0];
          float4 w1 = *(const float4*)&Ws0[(kb + k)*DD + c0 + 4];
          float4 u0 = *(const float4*)&Ws1[(kb + k)*DD + c0];
          float4 u1 = *(const float4*)&Ws1[(kb + k)*DD + c0 + 4];
          fma4x4(x0, w0, a0[0][0]); fma4x4(x0, w1, a0[0][1]);
          fma4x4(x1, w0, a0[1][0]); fma4x4(x1, w1, a0[1][1]);
          fma4x4(x0, u0, a1[0][0]); fma4x4(x0, u1, a1[0][1]);
          fma4x4(x1, u0, a1[1][0]); fma4x4(x1, u1, a1[1][1]);
        }
      } else {
        for (int k = 0; k < 32; ++k) {
          float4 x0 = *(const float4*)&Ht[k][tr*8];
          float4 x1 = *(const float4*)&Ht[k][tr*8 + 4];
          float4 w0 = *(const float4*)&Ws0[(kb + k)*DD + c0];
          float4 w1 = *(const float4*)&Ws0[(kb + k)*DD + c0 + 4];
          fma4x4(x0, w0, a0[0][0]); fma4x4(x0, w1, a0[0][1]);
          fma4x4(x1, w0, a0[1][0]); fma4x4(x1, w1, a0[1][1]);
        }
      }
    }
    #pragma unroll
    for (int a = 0; a < 2; ++a)
      #pragma unroll
      for (int i = 0; i < 4; ++i) {
        int row = row0 + tr*8 + a*4 + i;
        bool ok;
        if (pool == 0)      ok = (row < nvi);
        else if (pool == 1) ok = (row >= nvi && row < nmax);
        else                ok = (row < NH);
        if (ok) {
          *(float4*)&H[row*DD + c0]     = a0[a][0][i];
          *(float4*)&H[row*DD + c0 + 4] = a0[a][1][i];
          if (pool == 0) {
            *(float4*)&TA2[row*DD + c0]     = a1[a][0][i];
            *(float4*)&TA2[row*DD + c0 + 4] = a1[a][1][i];
          }
        }
      }
  }
}

// persistent edge kernel: cW1/cW2 transposed + cb resident in LDS.
__global__ __launch_bounds__(256, 2)
void k_edges(const int* __restrict__ edges,
             const float* __restrict__ TA, const float* __restrict__ TA2,
             const float* __restrict__ HU2,
             const float* __restrict__ rT, const float* __restrict__ qT,
             const float* __restrict__ cW1, const float* __restrict__ cb1,
             const float* __restrict__ cW2, const float* __restrict__ cb2,
             float* __restrict__ logits) {
  __shared__ __align__(16) float Wt1s[DD*68];
  __shared__ __align__(16) float Wt2s[DD*68];
  __shared__ __align__(16) float Lt[DD][68];
  __shared__ __align__(16) float Rt[DD][68];
  __shared__ __align__(16) float4 cbs4[2][16];
  __shared__ float lg[64];
  __shared__ int   se[64*8];
  const int tid = threadIdx.x;
  for (int i = tid; i < DD*DD; i += 256) {
    int k = i >> 6, d = i & 63;
    Wt1s[d*68 + k] = cW1[i];   // Wt[d][k] = cW[k][d]
    Wt2s[d*68 + k] = cW2[i];
  }
  if (tid < 16) {
    cbs4[0][tid] = *(const float4*)&cb1[tid*4];
    cbs4[1][tid] = *(const float4*)&cb2[tid*4];
  }
  const int e   = tid >> 2;
  const int d0  = (tid & 3) * 16;
  const int ee0 = (tid & 15) << 2;
  const int k0  = (tid >> 4) << 2;
  __syncthreads();
  const int NT = (NE + 63) / 64;
  for (int tile = blockIdx.x; tile < NT; tile += gridDim.x) {
    const int e0 = tile * 64;
    const int ecnt = min(64, NE - e0);
    for (int i = tid; i < 64*8; i += 256) se[i] = (i < ecnt*8) ? edges[e0*8 + i] : 0;
    if (tid < 64) lg[tid] = 0.f;
    __syncthreads();
    const int rel = se[e*8 + 3];
    const int eg  = se[e*8 + 0];
    const int li  = se[e*8 + 6];
    for (int g = 0; g < 2; ++g) {
      const float* Lb = g ? TA2 : TA;
      const float* Rb = g ? HU2 : TA;
      const float* rL = rT + (g ? 2*NR*DD : 0);
      const float* rR = rT + (g ? 3*NR*DD : 1*NR*DD);
      const float* qL = qT + (g ? 2*NB*DD : 0);
      const float* qR = qT + (g ? 3*NB*DD : 1*NB*DD);
      const float* Wts = g ? Wt2s : Wt1s;
      const int ri = g ? se[e*8 + 2] : se[e*8 + 7];
      float cbp = 0.f;
      #pragma unroll
      for (int di = 0; di < 4; ++di) {
        const int d = d0 + 4*di;
        float4 l = *(const float4*)&Lb[li*DD + d];
        float4 t = *(const float4*)&rL[rel*DD + d];
        float4 u = *(const float4*)&qL[eg*DD + d];
        l.x += t.x + u.x; l.y += t.y + u.y; l.z += t.z + u.z; l.w += t.w + u.w;
        l = leaky4(l);
        Lt[d+0][e] = l.x; Lt[d+1][e] = l.y; Lt[d+2][e] = l.z; Lt[d+3][e] = l.w;
        float4 c = cbs4[g][d >> 2];
        cbp += l.x*c.x + l.y*c.y + l.z*c.z + l.w*c.w;
        float4 r = *(const float4*)&Rb[ri*DD + d];
        t = *(const float4*)&rR[rel*DD + d];
        u = *(const float4*)&qR[eg*DD + d];
        r.x += t.x + u.x; r.y += t.y + u.y; r.z += t.z + u.z; r.w += t.w + u.w;
        r = leaky4(r);
        Rt[d+0][e] = r.x; Rt[d+1][e] = r.y; Rt[d+2][e] = r.z; Rt[d+3][e] = r.w;
      }
      atomicAdd(&lg[e], cbp);
      __syncthreads();
      float4 z[4] = {{0,0,0,0},{0,0,0,0},{0,0,0,0},{0,0,0,0}};
      for (int d = 0; d < DD; ++d) {
        float4 x = *(const float4*)&Lt[d][ee0];
        float4 w = *(const float4*)&Wts[d*68 + k0];
        fma4x4(x, w, z);
      }
      {
        float4 r0v = *(const float4*)&Rt[k0+0][ee0];
        float4 r1v = *(const float4*)&Rt[k0+1][ee0];
        float4 r2v = *(const float4*)&Rt[k0+2][ee0];
        float4 r3v = *(const float4*)&Rt[k0+3][ee0];
        float p0 = z[0].x*r0v.x + z[0].y*r1v.x + z[0].z*r2v.x + z[0].w*r3v.x;
        float p1 = z[1].x*r0v.y + z[1].y*r1v.y + z[1].z*r2v.y + z[1].w*r3v.y;
        float p2 = z[2].x*r0v.z + z[2].y*r1v.z + z[2].z*r2v.z + z[2].w*r3v.z;
        float p3 = z[3].x*r0v.w + z[3].y*r1v.w + z[3].z*r2v.w + z[3].w*r3v.w;
        atomicAdd(&lg[ee0+0], p0);
        atomicAdd(&lg[ee0+1], p1);
        atomicAdd(&lg[ee0+2], p2);
        atomicAdd(&lg[ee0+3], p3);
      }
      __syncthreads();
    }
    if (tid < ecnt) logits[e0 + tid] = lg[tid];
    __syncthreads();
  }
}

__global__ void k_softmax(const int* __restrict__ edges, const float* __restrict__ logits,
                          const float* __restrict__ na, float* __restrict__ out) {
  int e = blockIdx.x * blockDim.x + threadIdx.x;
  if (e >= NE) return;
  int seg = edges[e*8 + 4];
  if (e > 0 && edges[(e-1)*8 + 4] == seg) return;  // not a segment head
  int j = e;
  float m = -1e30f;
  while (j < NE && edges[j*8 + 4] == seg) { m = fmaxf(m, logits[j]); ++j; }
  float s = 0.f;
  for (int t = e; t < j; ++t) s += expf(logits[t] - m);
  int eg = edges[e*8 + 0], vi = edges[e*8 + 1];
  float scale = na[eg*NN + vi] / s;
  for (int t = e; t < j; ++t) {
    int vj = edges[t*8 + 2];
    __hip_atomic_fetch_add(&out[eg*NN + vj], expf(logits[t] - m) * scale,
                           __ATOMIC_RELAXED, __HIP_MEMORY_SCOPE_AGENT);
  }
}

__global__ void k_rowsum(const float* __restrict__ out, float* __restrict__ bsum) {
  int b = blockIdx.y;
  float s = 0.f;
  for (int n = blockIdx.x * blockDim.x + threadIdx.x; n < NN; n += gridDim.x * blockDim.x)
    s += out[b*NN + n];
  for (int off = 32; off > 0; off >>= 1) s += __shfl_down(s, off);
  if ((threadIdx.x & 63) == 0)
    __hip_atomic_fetch_add(&bsum[b], s, __ATOMIC_RELAXED, __HIP_MEMORY_SCOPE_AGENT);
}

__global__ void k_div(float* __restrict__ out, const float* __restrict__ bsum) {
  int i = blockIdx.x * blockDim.x + threadIdx.x;
  if (i < NB*NN) out[i] /= bsum[i / NN];
}

extern "C" void kernel_launch(void* const* d_in, const int* in_sizes, int n_in,
                              void* d_out, int out_size, void* d_ws, size_t ws_size,
                              hipStream_t stream) {
  (void)in_sizes; (void)n_in; (void)out_size; (void)ws_size;
  const float* na     = (const float*)d_in[0];
  const int*   edges  = (const int*)  d_in[1];
  const float* huncon = (const float*)d_in[2];
  const float* hcon   = (const float*)d_in[3];
  const float* rtab   = (const float*)d_in[4];
  const float* qh     = (const float*)d_in[5];
  const float* qr     = (const float*)d_in[6];
  const float* pW     = (const float*)d_in[7];
  const float* pb     = (const float*)d_in[8];
  const float* g1_lW  = (const float*)d_in[9];
  const float* g1_lb  = (const float*)d_in[10];
  const float* g1_rW  = (const float*)d_in[11];
  const float* g1_rb  = (const float*)d_in[12];
  const float* g1_cW  = (const float*)d_in[13];
  const float* g1_cb  = (const float*)d_in[14];
  const float* g2_lW  = (const float*)d_in[15];
  const float* g2_lb  = (const float*)d_in[16];
  const float* g2_rW  = (const float*)d_in[17];
  const float* g2_rb  = (const float*)d_in[18];
  const float* g2_cW  = (const float*)d_in[19];
  const float* g2_cb  = (const float*)d_in[20];
  float* out  = (float*)d_out;
  float* ws   = (float*)d_ws;
  int*   wsI  = (int*)d_ws;
  float* bsum = ws + 16;
  float* H    = ws + H_OFF;            // TA in-place; HU2 = H + NM*DD
  float* TA2  = ws + TA2_OFF;
  float* rT   = ws + RT_OFF;
  float* qT   = ws + QT_OFF;
  float* lgp  = ws + LG_OFF;

  hipMemsetAsync(d_out, 0, (size_t)NB*NN*sizeof(float), stream);
  k_init<<<1, 64, 0, stream>>>(wsI, bsum);
  k_limits<<<(NE + 255)/256, 256, 0, stream>>>(edges, wsI);
  k_tables<<<NR + NB, 64, 0, stream>>>(rtab, qh, qr, pW, pb,
                                       g1_lW, g1_lb, g1_rW, g1_rb,
                                       g2_lW, g2_lb, g2_rW, g2_rb, rT, qT);
  k_proj<<<512, 256, 0, stream>>>(hcon, huncon, pW, pb, wsI, H);
  k_tf<<<PA + PB + PC, 256, 0, stream>>>(g1_lW, g1_rW, g2_lW, g2_rW, wsI, H, TA2);
  k_edges<<<512, 256, 0, stream>>>(edges, H, TA2, H + NM*DD, rT, qT,
                                   g1_cW, g1_cb, g2_cW, g2_cb, lgp);
  k_softmax<<<(NE + 255)/256, 256, 0, stream>>>(edges, lgp, na, out);
  k_rowsum<<<dim3(32, 16), 256, 0, stream>>>(out, bsum);
  k_div<<<(NB*NN + 255)/256, 256, 0, stream>>>(out, bsum);
}